// Round 2
// baseline (1047.820 us; speedup 1.0000x reference)
//
#include <hip/hip_runtime.h>

// z_e [32,64,64,64] f32, emb [1024,64] f32, out flat index = c*N + n.
constexpr int Cdim = 64;
constexpr int Kcb  = 1024;
constexpr int HWs  = 64 * 64;
constexpr int Npts = 32 * HWs;
constexpr int PPB  = 64;    // points per block (one per lane)
constexpr int KSEC = 256;   // codes per wave (4 waves split K)

// Block = 256 threads = 4 waves. Wave w scans codes [w*256, w*256+256) for the
// block's 64 points (one point per lane). k stays wave-uniform -> e-rows load
// through the scalar path (SGPR operand into v_fma). 4x more waves than the
// round-1 layout -> latency hiding.
__global__ __launch_bounds__(256) void vq_argmin_gather_kernel(
    const float* __restrict__ ze,
    const float* __restrict__ emb,
    float* __restrict__ out) {
  __shared__ float en_s[Kcb];
  __shared__ float bestd_s[4][PPB];
  __shared__ int   bestk_s[4][PPB];

  const int t    = threadIdx.x;
  const int wave = t >> 6;
  const int lane = t & 63;

  // --- e-norm table (identical arithmetic to round 1) ---
  #pragma unroll
  for (int r = 0; r < 4; ++r) {
    const int k = t + r * 256;
    const float4* row = reinterpret_cast<const float4*>(emb + (k << 6));
    float a0 = 0.f, a1 = 0.f, a2 = 0.f, a3 = 0.f;
    #pragma unroll
    for (int j = 0; j < 16; ++j) {
      float4 v = row[j];
      a0 = fmaf(v.x, v.x, a0);
      a1 = fmaf(v.y, v.y, a1);
      a2 = fmaf(v.z, v.z, a2);
      a3 = fmaf(v.w, v.w, a3);
    }
    en_s[k] = (a0 + a1) + (a2 + a3);
  }
  __syncthreads();

  // --- this lane's point (same point for all 4 waves; reads are L2/L3-warm) ---
  const int n  = blockIdx.x * PPB + lane;
  const int b  = n >> 12;
  const int hw = n & (HWs - 1);
  const float* xp = ze + (b * Cdim) * HWs + hw;
  float x[Cdim];
  #pragma unroll
  for (int c = 0; c < Cdim; ++c) x[c] = xp[c * HWs];

  float xn0 = 0.f, xn1 = 0.f, xn2 = 0.f, xn3 = 0.f;
  #pragma unroll
  for (int c = 0; c < Cdim; c += 4) {
    xn0 = fmaf(x[c + 0], x[c + 0], xn0);
    xn1 = fmaf(x[c + 1], x[c + 1], xn1);
    xn2 = fmaf(x[c + 2], x[c + 2], xn2);
    xn3 = fmaf(x[c + 3], x[c + 3], xn3);
  }
  const float xnorm = (xn0 + xn1) + (xn2 + xn3);

  // --- scan this wave's 256 codes; k wave-uniform each iteration ---
  float best  = 3.4e38f;
  int   bestk = 0;
  const int kbase = wave * KSEC;
  #pragma unroll 2
  for (int kk = 0; kk < KSEC; ++kk) {
    const int k = kbase + kk;
    const float4* er = reinterpret_cast<const float4*>(emb + (k << 6));
    float d0 = 0.f, d1 = 0.f, d2 = 0.f, d3 = 0.f;
    #pragma unroll
    for (int j = 0; j < 16; ++j) {
      float4 v = er[j];
      d0 = fmaf(x[4 * j + 0], v.x, d0);
      d1 = fmaf(x[4 * j + 1], v.y, d1);
      d2 = fmaf(x[4 * j + 2], v.z, d2);
      d3 = fmaf(x[4 * j + 3], v.w, d3);
    }
    const float dot = (d0 + d1) + (d2 + d3);
    const float tt  = xnorm + en_s[k];
    const float d   = __fsub_rn(tt, __fmul_rn(2.0f, dot));
    if (d < best) { best = d; bestk = k; }  // strict <: first-min within wave
  }

  bestd_s[wave][lane] = best;
  bestk_s[wave][lane] = bestk;
  __syncthreads();

  // --- combine the 4 wave-partials for point p (redundantly in every wave).
  // Ascending wave order + strict < == ascending-k first-min, numpy-compatible.
  const int p = lane;
  float bd = bestd_s[0][p];
  int   bk = bestk_s[0][p];
  #pragma unroll
  for (int w = 1; w < 4; ++w) {
    const float dw = bestd_s[w][p];
    const int   kw = bestk_s[w][p];
    if (dw < bd) { bd = dw; bk = kw; }
  }

  // --- epilogue: wave w writes channels [16w, 16w+16) for its lane's point ---
  const int np = blockIdx.x * PPB + p;
  const int c0 = wave * 16;
  const float4* brow = reinterpret_cast<const float4*>(emb + (bk << 6) + c0);
  #pragma unroll
  for (int j = 0; j < 4; ++j) {
    float4 v = brow[j];
    out[(c0 + 4 * j + 0) * Npts + np] = v.x;
    out[(c0 + 4 * j + 1) * Npts + np] = v.y;
    out[(c0 + 4 * j + 2) * Npts + np] = v.z;
    out[(c0 + 4 * j + 3) * Npts + np] = v.w;
  }
}

extern "C" void kernel_launch(void* const* d_in, const int* in_sizes, int n_in,
                              void* d_out, int out_size, void* d_ws, size_t ws_size,
                              hipStream_t stream) {
  (void)in_sizes; (void)n_in; (void)d_ws; (void)ws_size; (void)out_size;
  const float* ze  = (const float*)d_in[0];
  const float* emb = (const float*)d_in[1];
  float* out = (float*)d_out;

  vq_argmin_gather_kernel<<<Npts / PPB, 256, 0, stream>>>(ze, emb, out);
}

// Round 4
// 330.121 us; speedup vs baseline: 3.1740x; 3.1740x over previous
//
#include <hip/hip_runtime.h>

// z_e [32,64,64,64] f32, emb [1024,64] f32, out flat index = c*N + n.
constexpr int Cdim = 64;
constexpr int Kcb  = 1024;
constexpr int HWs  = 64 * 64;
constexpr int Npts = 32 * HWs;
constexpr int PPB  = 64;    // points per block (one per lane)
constexpr int KSEC = 256;   // codes per wave (4 waves split K)

// Block = 256 threads = 4 waves. Wave w scans codes [w*256, w*256+256) for the
// block's 64 points (one point per lane). readfirstlane(wave) makes kbase
// provably wave-uniform -> e-row loads stay on the scalar (s_load) path.
__global__ __launch_bounds__(256) void vq_argmin_gather_kernel(
    const float* __restrict__ ze,
    const float* __restrict__ emb,
    float* __restrict__ out) {
  __shared__ float en_s[Kcb];
  __shared__ float bestd_s[4][PPB];
  __shared__ int   bestk_s[4][PPB];

  const int t    = threadIdx.x;
  const int wave = t >> 6;
  const int lane = t & 63;

  // --- e-norm table (identical arithmetic to rounds 1-2) ---
  #pragma unroll
  for (int r = 0; r < 4; ++r) {
    const int k = t + r * 256;
    const float4* row = reinterpret_cast<const float4*>(emb + (k << 6));
    float a0 = 0.f, a1 = 0.f, a2 = 0.f, a3 = 0.f;
    #pragma unroll
    for (int j = 0; j < 16; ++j) {
      float4 v = row[j];
      a0 = fmaf(v.x, v.x, a0);
      a1 = fmaf(v.y, v.y, a1);
      a2 = fmaf(v.z, v.z, a2);
      a3 = fmaf(v.w, v.w, a3);
    }
    en_s[k] = (a0 + a1) + (a2 + a3);
  }
  __syncthreads();

  // --- this lane's point ---
  const int n  = blockIdx.x * PPB + lane;
  const int b  = n >> 12;
  const int hw = n & (HWs - 1);
  const float* xp = ze + (b * Cdim) * HWs + hw;
  float x[Cdim];
  #pragma unroll
  for (int c = 0; c < Cdim; ++c) x[c] = xp[c * HWs];

  float xn0 = 0.f, xn1 = 0.f, xn2 = 0.f, xn3 = 0.f;
  #pragma unroll
  for (int c = 0; c < Cdim; c += 4) {
    xn0 = fmaf(x[c + 0], x[c + 0], xn0);
    xn1 = fmaf(x[c + 1], x[c + 1], xn1);
    xn2 = fmaf(x[c + 2], x[c + 2], xn2);
    xn3 = fmaf(x[c + 3], x[c + 3], xn3);
  }
  const float xnorm = (xn0 + xn1) + (xn2 + xn3);

  // --- scan this wave's 256 codes; kbase forced into an SGPR so the
  // compiler proves uniformity and keeps e-row loads scalar (s_load). ---
  const int wu    = __builtin_amdgcn_readfirstlane(wave);
  const int kbase = wu * KSEC;
  float best  = 3.4e38f;
  int   bestk = 0;
  #pragma unroll 2
  for (int kk = 0; kk < KSEC; ++kk) {
    const int k = kbase + kk;
    const float4* er = reinterpret_cast<const float4*>(emb + (k << 6));
    float d0 = 0.f, d1 = 0.f, d2 = 0.f, d3 = 0.f;
    #pragma unroll
    for (int j = 0; j < 16; ++j) {
      float4 v = er[j];
      d0 = fmaf(x[4 * j + 0], v.x, d0);
      d1 = fmaf(x[4 * j + 1], v.y, d1);
      d2 = fmaf(x[4 * j + 2], v.z, d2);
      d3 = fmaf(x[4 * j + 3], v.w, d3);
    }
    const float dot = (d0 + d1) + (d2 + d3);
    const float tt  = xnorm + en_s[k];
    const float d   = __fsub_rn(tt, __fmul_rn(2.0f, dot));
    if (d < best) { best = d; bestk = k; }  // strict <: first-min within wave
  }

  bestd_s[wave][lane] = best;
  bestk_s[wave][lane] = bestk;
  __syncthreads();

  // --- combine the 4 wave-partials (ascending wave order + strict < ==
  // ascending-k first-min, numpy-compatible) ---
  const int p = lane;
  float bd = bestd_s[0][p];
  int   bk = bestk_s[0][p];
  #pragma unroll
  for (int w = 1; w < 4; ++w) {
    const float dw = bestd_s[w][p];
    const int   kw = bestk_s[w][p];
    if (dw < bd) { bd = dw; bk = kw; }
  }

  // --- epilogue: wave w writes channels [16w, 16w+16) for its lane's point ---
  const int np = blockIdx.x * PPB + p;
  const int c0 = wave * 16;
  const float4* brow = reinterpret_cast<const float4*>(emb + (bk << 6) + c0);
  #pragma unroll
  for (int j = 0; j < 4; ++j) {
    float4 v = brow[j];
    out[(c0 + 4 * j + 0) * Npts + np] = v.x;
    out[(c0 + 4 * j + 1) * Npts + np] = v.y;
    out[(c0 + 4 * j + 2) * Npts + np] = v.z;
    out[(c0 + 4 * j + 3) * Npts + np] = v.w;
  }
}

extern "C" void kernel_launch(void* const* d_in, const int* in_sizes, int n_in,
                              void* d_out, int out_size, void* d_ws, size_t ws_size,
                              hipStream_t stream) {
  (void)in_sizes; (void)n_in; (void)d_ws; (void)ws_size; (void)out_size;
  const float* ze  = (const float*)d_in[0];
  const float* emb = (const float*)d_in[1];
  float* out = (float*)d_out;

  vq_argmin_gather_kernel<<<Npts / PPB, 256, 0, stream>>>(ze, emb, out);
}

// Round 5
// 296.470 us; speedup vs baseline: 3.5343x; 1.1135x over previous
//
#include <hip/hip_runtime.h>
#include <hip/hip_bf16.h>

using short8 = __attribute__((ext_vector_type(8))) short;
using f32x4  = __attribute__((ext_vector_type(4))) float;

constexpr int Cdim = 64, Kcb = 1024, HWs = 4096;
constexpr int Npts = 131072;
constexpr float MARGIN = 0.02f;

// ws layout (bytes)
constexpr size_t WS_EH   = 0;                      // [8][1024][8] bf16
constexpr size_t WS_EL   = 131072;                 // [8][1024][8] bf16
constexpr size_t WS_EN   = 262144;                 // f32[1024]
constexpr size_t WS_CNT  = 266240;                 // u32 counter
constexpr size_t WS_LIST = 266304;                 // u32[Npts]
constexpr size_t WS_NEED = WS_LIST + 4 * (size_t)Npts;

// ---------- prep: split emb into bf16 hi/lo planes + exact f32 norms ----------
__global__ void vq_prep(const float* __restrict__ emb, unsigned short* __restrict__ eh,
                        unsigned short* __restrict__ el, float* __restrict__ en) {
  const int k = blockIdx.x * 256 + threadIdx.x;
  if (k >= Kcb) return;
  const float4* row = reinterpret_cast<const float4*>(emb + (k << 6));
  float a0 = 0.f, a1 = 0.f, a2 = 0.f, a3 = 0.f;
  #pragma unroll
  for (int j = 0; j < 16; ++j) {
    float4 v = row[j];
    a0 = fmaf(v.x, v.x, a0); a1 = fmaf(v.y, v.y, a1);
    a2 = fmaf(v.z, v.z, a2); a3 = fmaf(v.w, v.w, a3);
    float vv[4] = {v.x, v.y, v.z, v.w};
    #pragma unroll
    for (int q = 0; q < 4; ++q) {
      const int c = 4 * j + q;
      const float x = vv[q];
      const unsigned short hs = __builtin_bit_cast(unsigned short, __float2bfloat16(x));
      const float hf = __builtin_bit_cast(float, (unsigned)hs << 16);
      const unsigned short ls = __builtin_bit_cast(unsigned short, __float2bfloat16(x - hf));
      const int idx = ((c >> 3) * Kcb + k) * 8 + (c & 7);
      eh[idx] = hs; el[idx] = ls;
    }
  }
  en[k] = (a0 + a1) + (a2 + a3);  // same 4-acc order as the exact fallback
}

// ---------- main: MFMA approx scan + best/2nd tracking + gather ----------
__global__ __launch_bounds__(256, 4) void vq_main(
    const float* __restrict__ ze, const float* __restrict__ emb,
    const unsigned short* __restrict__ eh, const unsigned short* __restrict__ el,
    const float* __restrict__ en, float* __restrict__ out,
    unsigned int* __restrict__ cnt, unsigned int* __restrict__ list, unsigned int listcap) {
  __shared__ unsigned short ebuf[2][8][128][8];   // [h/l][cblock][code-in-chunk][8] = 32 KB
  __shared__ __align__(16) float en_s[Kcb];       // 4 KB

  const int t = threadIdx.x;
  const int wave = t >> 6, lane = t & 63;
  const int g = lane >> 4, i16 = lane & 15;

  #pragma unroll
  for (int r = 0; r < 4; ++r) en_s[t + 256 * r] = en[t + 256 * r];

  // ---- B frags: this wave's 32 points (2 ptiles of 16) ----
  const int pbase = blockIdx.x * 128 + wave * 32;
  short8 Bh[2][2], Bl[2][2];   // [ptile][c-step]
  #pragma unroll
  for (int p = 0; p < 2; ++p) {
    const int n = pbase + p * 16 + i16;
    const int b = n >> 12, hw = n & (HWs - 1);
    const float* xb = ze + (size_t)b * (Cdim * HWs) + hw;
    #pragma unroll
    for (int cs = 0; cs < 2; ++cs) {
      short8 fh, fl;
      #pragma unroll
      for (int j = 0; j < 8; ++j) {
        const int c = cs * 32 + g * 8 + j;
        const float x = xb[c * HWs];
        const unsigned short hs = __builtin_bit_cast(unsigned short, __float2bfloat16(x));
        const float hf = __builtin_bit_cast(float, (unsigned)hs << 16);
        const unsigned short ls = __builtin_bit_cast(unsigned short, __float2bfloat16(x - hf));
        fh[j] = (short)hs; fl[j] = (short)ls;
      }
      Bh[p][cs] = fh; Bl[p][cs] = fl;
    }
  }

  float bd[2][4], bd2[2][4]; int bt[2][4];
  #pragma unroll
  for (int p = 0; p < 2; ++p)
    #pragma unroll
    for (int r = 0; r < 4; ++r) { bd[p][r] = 3.4e38f; bd2[p][r] = 3.4e38f; bt[p][r] = 0; }

  #pragma unroll 1
  for (int cc = 0; cc < 8; ++cc) {       // 8 chunks of 128 codes
    __syncthreads();
    // stage 32 KB chunk (reg-staged, coalesced, linear LDS image)
    #pragma unroll
    for (int q = 0; q < 8; ++q) {
      const int off16 = q * 256 + t;             // 16B units within chunk image
      const int pp = off16 >> 7;                 // piece: 0..7=eh planes, 8..15=el planes
      const int inpiece = off16 & 127;
      const unsigned short* src = (pp < 8 ? eh : el)
          + (pp & 7) * (Kcb * 8) + cc * 1024 + inpiece * 8;
      float4 v = *reinterpret_cast<const float4*>(src);
      *reinterpret_cast<float4*>(&reinterpret_cast<unsigned short*>(ebuf)[off16 * 8]) = v;
    }
    __syncthreads();

    for (int ct = 0; ct < 8; ++ct) {
      const int tile = cc * 8 + ct;
      const short8 Ah0 = *reinterpret_cast<const short8*>(&ebuf[0][0 + g][ct * 16 + i16][0]);
      const short8 Ah1 = *reinterpret_cast<const short8*>(&ebuf[0][4 + g][ct * 16 + i16][0]);
      const short8 Al0 = *reinterpret_cast<const short8*>(&ebuf[1][0 + g][ct * 16 + i16][0]);
      const short8 Al1 = *reinterpret_cast<const short8*>(&ebuf[1][4 + g][ct * 16 + i16][0]);
      const f32x4 enf = reinterpret_cast<const f32x4*>(en_s)[tile * 4 + g];
      f32x4 acc0 = {0.f, 0.f, 0.f, 0.f}, acc1 = {0.f, 0.f, 0.f, 0.f};
      acc0 = __builtin_amdgcn_mfma_f32_16x16x32_bf16(Ah0, Bh[0][0], acc0, 0, 0, 0);
      acc1 = __builtin_amdgcn_mfma_f32_16x16x32_bf16(Ah0, Bh[1][0], acc1, 0, 0, 0);
      acc0 = __builtin_amdgcn_mfma_f32_16x16x32_bf16(Ah1, Bh[0][1], acc0, 0, 0, 0);
      acc1 = __builtin_amdgcn_mfma_f32_16x16x32_bf16(Ah1, Bh[1][1], acc1, 0, 0, 0);
      acc0 = __builtin_amdgcn_mfma_f32_16x16x32_bf16(Ah0, Bl[0][0], acc0, 0, 0, 0);
      acc1 = __builtin_amdgcn_mfma_f32_16x16x32_bf16(Ah0, Bl[1][0], acc1, 0, 0, 0);
      acc0 = __builtin_amdgcn_mfma_f32_16x16x32_bf16(Ah1, Bl[0][1], acc0, 0, 0, 0);
      acc1 = __builtin_amdgcn_mfma_f32_16x16x32_bf16(Ah1, Bl[1][1], acc1, 0, 0, 0);
      acc0 = __builtin_amdgcn_mfma_f32_16x16x32_bf16(Al0, Bh[0][0], acc0, 0, 0, 0);
      acc1 = __builtin_amdgcn_mfma_f32_16x16x32_bf16(Al0, Bh[1][0], acc1, 0, 0, 0);
      acc0 = __builtin_amdgcn_mfma_f32_16x16x32_bf16(Al1, Bh[0][1], acc0, 0, 0, 0);
      acc1 = __builtin_amdgcn_mfma_f32_16x16x32_bf16(Al1, Bh[1][1], acc1, 0, 0, 0);
      #pragma unroll
      for (int r = 0; r < 4; ++r) {
        const float d0 = fmaf(-2.0f, acc0[r], enf[r]);
        const bool lt0 = d0 < bd[0][r];
        bd2[0][r] = fminf(bd2[0][r], fmaxf(d0, bd[0][r]));
        bd[0][r]  = fminf(bd[0][r], d0);
        bt[0][r]  = lt0 ? tile : bt[0][r];
        const float d1 = fmaf(-2.0f, acc1[r], enf[r]);
        const bool lt1 = d1 < bd[1][r];
        bd2[1][r] = fminf(bd2[1][r], fmaxf(d1, bd[1][r]));
        bd[1][r]  = fminf(bd[1][r], d1);
        bt[1][r]  = lt1 ? tile : bt[1][r];
      }
    }
  }

  // ---- finalize per ptile: merge 4 reg-streams, then 4 lane-groups ----
  const unsigned long long lanebit = 1ull << lane;
  #pragma unroll
  for (int p = 0; p < 2; ++p) {
    float fb = bd[p][0];
    float f2 = bd2[p][0];
    int   fk = bt[p][0] * 16 + g * 4 + 0;
    #pragma unroll
    for (int r = 1; r < 4; ++r) {
      const float dr = bd[p][r];
      const int   kr = bt[p][r] * 16 + g * 4 + r;
      f2 = fminf(fminf(f2, bd2[p][r]), fmaxf(fb, dr));
      const bool take = dr < fb;     // cross-stream ties fall inside MARGIN -> risky path
      fb = take ? dr : fb;
      fk = take ? kr : fk;
    }
    #pragma unroll
    for (int m = 16; m <= 32; m <<= 1) {
      const float od = __shfl_xor(fb, m, 64);
      const int   ok = __shfl_xor(fk, m, 64);
      const float o2 = __shfl_xor(f2, m, 64);
      f2 = fminf(fminf(f2, o2), fmaxf(fb, od));
      const bool take = (od < fb) || (od == fb && ok < fk);
      fb = take ? od : fb;
      fk = take ? ok : fk;
    }
    const int n = pbase + p * 16 + i16;
    // gather winning row; wave group g writes channels [16g, 16g+16)
    const float4* er = reinterpret_cast<const float4*>(emb + (fk << 6) + g * 16);
    #pragma unroll
    for (int jj = 0; jj < 4; ++jj) {
      float4 v = er[jj];
      out[(size_t)(g * 16 + 4 * jj + 0) * Npts + n] = v.x;
      out[(size_t)(g * 16 + 4 * jj + 1) * Npts + n] = v.y;
      out[(size_t)(g * 16 + 4 * jj + 2) * Npts + n] = v.z;
      out[(size_t)(g * 16 + 4 * jj + 3) * Npts + n] = v.w;
    }
    // risky append (g==0 lanes represent the 16 points)
    const bool risky = (g == 0) && (f2 - fb <= MARGIN);
    const unsigned long long msk = __ballot(risky);
    if (msk) {
      unsigned basev = 0;
      if (lane == 0) basev = atomicAdd(cnt, (unsigned)__popcll(msk));
      basev = (unsigned)__shfl((int)basev, 0, 64);
      if (risky) {
        const unsigned pos = basev + (unsigned)__popcll(msk & (lanebit - 1));
        if (pos < listcap) list[pos] = (unsigned)n;
      }
    }
  }
}

// ---------- fallback: exact round-1 arithmetic for risky points (1 wave/point) ----------
__global__ __launch_bounds__(256) void vq_fix(
    const float* __restrict__ ze, const float* __restrict__ emb, float* __restrict__ out,
    const unsigned int* __restrict__ cnt, const unsigned int* __restrict__ list,
    unsigned int listcap) {
  __shared__ float en_s[Kcb];
  const int t = threadIdx.x;
  const int wave = t >> 6, lane = t & 63;
  #pragma unroll
  for (int r = 0; r < 4; ++r) {
    const int k = t + r * 256;
    const float4* row = reinterpret_cast<const float4*>(emb + (k << 6));
    float a0 = 0.f, a1 = 0.f, a2 = 0.f, a3 = 0.f;
    #pragma unroll
    for (int j = 0; j < 16; ++j) {
      float4 v = row[j];
      a0 = fmaf(v.x, v.x, a0); a1 = fmaf(v.y, v.y, a1);
      a2 = fmaf(v.z, v.z, a2); a3 = fmaf(v.w, v.w, a3);
    }
    en_s[k] = (a0 + a1) + (a2 + a3);
  }
  __syncthreads();
  unsigned count = *cnt;
  if (count > listcap) count = listcap;
  const int wid = __builtin_amdgcn_readfirstlane(blockIdx.x * 4 + wave);
  for (unsigned i = wid; i < count; i += 512) {
    const int n = (int)list[i];
    const int b = n >> 12, hw = n & (HWs - 1);
    const float* xp = ze + (size_t)b * (Cdim * HWs) + hw;
    float x[Cdim];
    #pragma unroll
    for (int c = 0; c < Cdim; ++c) x[c] = xp[c * HWs];
    float xn0 = 0.f, xn1 = 0.f, xn2 = 0.f, xn3 = 0.f;
    #pragma unroll
    for (int c = 0; c < Cdim; c += 4) {
      xn0 = fmaf(x[c], x[c], xn0);     xn1 = fmaf(x[c + 1], x[c + 1], xn1);
      xn2 = fmaf(x[c + 2], x[c + 2], xn2); xn3 = fmaf(x[c + 3], x[c + 3], xn3);
    }
    const float xnorm = (xn0 + xn1) + (xn2 + xn3);
    float best = 3.4e38f; int bestk = 0;
    for (int kk = 0; kk < 16; ++kk) {
      const int k = lane * 16 + kk;   // ascending within lane
      const float4* er2 = reinterpret_cast<const float4*>(emb + (k << 6));
      float d0 = 0.f, d1 = 0.f, d2 = 0.f, d3 = 0.f;
      #pragma unroll
      for (int j = 0; j < 16; ++j) {
        float4 v = er2[j];
        d0 = fmaf(x[4 * j + 0], v.x, d0); d1 = fmaf(x[4 * j + 1], v.y, d1);
        d2 = fmaf(x[4 * j + 2], v.z, d2); d3 = fmaf(x[4 * j + 3], v.w, d3);
      }
      const float dot = (d0 + d1) + (d2 + d3);
      const float tt = xnorm + en_s[k];
      const float d = __fsub_rn(tt, __fmul_rn(2.0f, dot));
      if (d < best) { best = d; bestk = k; }
    }
    // lexicographic (d, k) wave reduce == global ascending-k first-min
    #pragma unroll
    for (int m = 1; m < 64; m <<= 1) {
      const float od = __shfl_xor(best, m, 64);
      const int   ok = __shfl_xor(bestk, m, 64);
      const bool take = (od < best) || (od == best && ok < bestk);
      best = take ? od : best;
      bestk = take ? ok : bestk;
    }
    out[(size_t)lane * Npts + n] = emb[(bestk << 6) + lane];
  }
}

// ---------- safety net (ws too small): round-4 proven kernel ----------
__global__ __launch_bounds__(256) void vq_direct(
    const float* __restrict__ ze, const float* __restrict__ emb, float* __restrict__ out) {
  __shared__ float en_s[Kcb];
  __shared__ float bestd_s[4][64];
  __shared__ int   bestk_s[4][64];
  const int t = threadIdx.x, wave = t >> 6, lane = t & 63;
  #pragma unroll
  for (int r = 0; r < 4; ++r) {
    const int k = t + r * 256;
    const float4* row = reinterpret_cast<const float4*>(emb + (k << 6));
    float a0 = 0.f, a1 = 0.f, a2 = 0.f, a3 = 0.f;
    #pragma unroll
    for (int j = 0; j < 16; ++j) {
      float4 v = row[j];
      a0 = fmaf(v.x, v.x, a0); a1 = fmaf(v.y, v.y, a1);
      a2 = fmaf(v.z, v.z, a2); a3 = fmaf(v.w, v.w, a3);
    }
    en_s[k] = (a0 + a1) + (a2 + a3);
  }
  __syncthreads();
  const int n = blockIdx.x * 64 + lane;
  const int b = n >> 12, hw = n & (HWs - 1);
  const float* xp = ze + (b * Cdim) * HWs + hw;
  float x[Cdim];
  #pragma unroll
  for (int c = 0; c < Cdim; ++c) x[c] = xp[c * HWs];
  float xn0 = 0.f, xn1 = 0.f, xn2 = 0.f, xn3 = 0.f;
  #pragma unroll
  for (int c = 0; c < Cdim; c += 4) {
    xn0 = fmaf(x[c], x[c], xn0); xn1 = fmaf(x[c + 1], x[c + 1], xn1);
    xn2 = fmaf(x[c + 2], x[c + 2], xn2); xn3 = fmaf(x[c + 3], x[c + 3], xn3);
  }
  const float xnorm = (xn0 + xn1) + (xn2 + xn3);
  const int wu = __builtin_amdgcn_readfirstlane(wave);
  const int kbase = wu * 256;
  float best = 3.4e38f; int bestk = 0;
  #pragma unroll 2
  for (int kk = 0; kk < 256; ++kk) {
    const int k = kbase + kk;
    const float4* er = reinterpret_cast<const float4*>(emb + (k << 6));
    float d0 = 0.f, d1 = 0.f, d2 = 0.f, d3 = 0.f;
    #pragma unroll
    for (int j = 0; j < 16; ++j) {
      float4 v = er[j];
      d0 = fmaf(x[4 * j + 0], v.x, d0); d1 = fmaf(x[4 * j + 1], v.y, d1);
      d2 = fmaf(x[4 * j + 2], v.z, d2); d3 = fmaf(x[4 * j + 3], v.w, d3);
    }
    const float dot = (d0 + d1) + (d2 + d3);
    const float tt = xnorm + en_s[k];
    const float d = __fsub_rn(tt, __fmul_rn(2.0f, dot));
    if (d < best) { best = d; bestk = k; }
  }
  bestd_s[wave][lane] = best; bestk_s[wave][lane] = bestk;
  __syncthreads();
  float bdv = bestd_s[0][lane]; int bkv = bestk_s[0][lane];
  #pragma unroll
  for (int w = 1; w < 4; ++w) {
    const float dw = bestd_s[w][lane]; const int kw = bestk_s[w][lane];
    if (dw < bdv) { bdv = dw; bkv = kw; }
  }
  const int np = blockIdx.x * 64 + lane;
  const int c0 = wave * 16;
  const float4* brow = reinterpret_cast<const float4*>(emb + (bkv << 6) + c0);
  #pragma unroll
  for (int j = 0; j < 4; ++j) {
    float4 v = brow[j];
    out[(c0 + 4 * j + 0) * Npts + np] = v.x;
    out[(c0 + 4 * j + 1) * Npts + np] = v.y;
    out[(c0 + 4 * j + 2) * Npts + np] = v.z;
    out[(c0 + 4 * j + 3) * Npts + np] = v.w;
  }
}

extern "C" void kernel_launch(void* const* d_in, const int* in_sizes, int n_in,
                              void* d_out, int out_size, void* d_ws, size_t ws_size,
                              hipStream_t stream) {
  (void)in_sizes; (void)n_in; (void)out_size;
  const float* ze  = (const float*)d_in[0];
  const float* emb = (const float*)d_in[1];
  float* out = (float*)d_out;

  if (ws_size < WS_NEED) {   // safety net: proven round-4 path
    vq_direct<<<Npts / 64, 256, 0, stream>>>(ze, emb, out);
    return;
  }
  unsigned char* ws = (unsigned char*)d_ws;
  unsigned short* eh = (unsigned short*)(ws + WS_EH);
  unsigned short* el = (unsigned short*)(ws + WS_EL);
  float* en          = (float*)(ws + WS_EN);
  unsigned* cnt      = (unsigned*)(ws + WS_CNT);
  unsigned* list     = (unsigned*)(ws + WS_LIST);

  hipMemsetAsync(cnt, 0, 4, stream);
  vq_prep<<<4, 256, 0, stream>>>(emb, eh, el, en);
  vq_main<<<Npts / 128, 256, 0, stream>>>(ze, emb, eh, el, en, out, cnt, list, (unsigned)Npts);
  vq_fix<<<128, 256, 0, stream>>>(ze, emb, out, cnt, list, (unsigned)Npts);
}

// Round 6
// 245.725 us; speedup vs baseline: 4.2642x; 1.2065x over previous
//
#include <hip/hip_runtime.h>
#include <hip/hip_bf16.h>

using short8 = __attribute__((ext_vector_type(8))) short;
using f32x4  = __attribute__((ext_vector_type(4))) float;

constexpr int Cdim = 64, Kcb = 1024, HWs = 4096;
constexpr int Npts = 131072;
constexpr int PTS  = 256;            // points per block (4 waves x 4 ptiles x 16)
constexpr float MARGIN = 0.02f;

// ws layout (bytes)
constexpr size_t WS_EH   = 0;        // [8][1024][8] bf16 hi planes
constexpr size_t WS_EL   = 131072;   // [8][1024][8] bf16 lo planes
constexpr size_t WS_EN   = 262144;   // f32[1024] exact norms
constexpr size_t WS_CNT  = 266240;   // u32 risky counter
constexpr size_t WS_LIST = 266304;   // u32[Npts] risky list
constexpr size_t WS_NEED = WS_LIST + 4 * (size_t)Npts;

// ---------- prep: split emb into bf16 hi/lo planes + exact f32 norms ----------
__global__ void vq_prep(const float* __restrict__ emb, unsigned short* __restrict__ eh,
                        unsigned short* __restrict__ el, float* __restrict__ en) {
  const int k = blockIdx.x * 64 + threadIdx.x;
  if (k >= Kcb) return;
  const float4* row = reinterpret_cast<const float4*>(emb + (k << 6));
  float a0 = 0.f, a1 = 0.f, a2 = 0.f, a3 = 0.f;
  #pragma unroll
  for (int j = 0; j < 16; ++j) {
    float4 v = row[j];
    a0 = fmaf(v.x, v.x, a0); a1 = fmaf(v.y, v.y, a1);
    a2 = fmaf(v.z, v.z, a2); a3 = fmaf(v.w, v.w, a3);
    float vv[4] = {v.x, v.y, v.z, v.w};
    #pragma unroll
    for (int q = 0; q < 4; ++q) {
      const int c = 4 * j + q;
      const float x = vv[q];
      const unsigned short hs = __builtin_bit_cast(unsigned short, __float2bfloat16(x));
      const float hf = __builtin_bit_cast(float, (unsigned)hs << 16);
      const unsigned short ls = __builtin_bit_cast(unsigned short, __float2bfloat16(x - hf));
      const int idx = ((c >> 3) * Kcb + k) * 8 + (c & 7);
      eh[idx] = hs; el[idx] = ls;
    }
  }
  en[k] = (a0 + a1) + (a2 + a3);   // 4-acc order: matches vq_fix usage exactly
}

// ---------- main: MFMA approx scan + best/2nd tracking + staged gather ----------
__global__ __launch_bounds__(256, 2) void vq_main(
    const float* __restrict__ ze, const float* __restrict__ emb,
    const unsigned short* __restrict__ eh, const unsigned short* __restrict__ el,
    const float* __restrict__ en, float* __restrict__ out,
    unsigned int* __restrict__ cnt, unsigned int* __restrict__ list, unsigned int listcap) {
  __shared__ unsigned short ebuf[2][8][128][8];   // 32 KB: [h/l][cblock][code][8]
  __shared__ __align__(16) float en_s[Kcb];       // 4 KB
  __shared__ int klds[PTS];                       // 1 KB winning index per point

  const int t = threadIdx.x;
  const int wave = t >> 6, lane = t & 63;
  const int g = lane >> 4, i16 = lane & 15;

  #pragma unroll
  for (int r = 0; r < 4; ++r) en_s[t + 256 * r] = en[t + 256 * r];

  // ---- B frags: this wave's 64 points (4 ptiles of 16); z_e loads nontemporal ----
  const int pbase = blockIdx.x * PTS + wave * 64;
  short8 Bh[4][2], Bl[4][2];
  #pragma unroll
  for (int p = 0; p < 4; ++p) {
    const int n = pbase + p * 16 + i16;
    const int b = n >> 12, hw = n & (HWs - 1);
    const float* xb = ze + (size_t)b * (Cdim * HWs) + hw;
    #pragma unroll
    for (int cs = 0; cs < 2; ++cs) {
      short8 fh, fl;
      #pragma unroll
      for (int j = 0; j < 8; ++j) {
        const int c = cs * 32 + g * 8 + j;
        const float x = __builtin_nontemporal_load(xb + c * HWs);
        const unsigned short hs = __builtin_bit_cast(unsigned short, __float2bfloat16(x));
        const float hf = __builtin_bit_cast(float, (unsigned)hs << 16);
        const unsigned short ls = __builtin_bit_cast(unsigned short, __float2bfloat16(x - hf));
        fh[j] = (short)hs; fl[j] = (short)ls;
      }
      Bh[p][cs] = fh; Bl[p][cs] = fl;
    }
  }

  float bd[4][4], bd2[4][4]; int bt[4][4];
  #pragma unroll
  for (int p = 0; p < 4; ++p)
    #pragma unroll
    for (int r = 0; r < 4; ++r) { bd[p][r] = 3.4e38f; bd2[p][r] = 3.4e38f; bt[p][r] = 0; }

  #pragma unroll 1
  for (int cc = 0; cc < 8; ++cc) {       // 8 chunks of 128 codes
    __syncthreads();
    #pragma unroll
    for (int q = 0; q < 8; ++q) {        // stage 32 KB chunk
      const int off16 = q * 256 + t;
      const int pp = off16 >> 7;
      const int inpiece = off16 & 127;
      const unsigned short* src = (pp < 8 ? eh : el)
          + (pp & 7) * (Kcb * 8) + cc * 1024 + inpiece * 8;
      float4 v = *reinterpret_cast<const float4*>(src);
      *reinterpret_cast<float4*>(&reinterpret_cast<unsigned short*>(ebuf)[off16 * 8]) = v;
    }
    __syncthreads();

    for (int ct = 0; ct < 8; ++ct) {
      const int tile = cc * 8 + ct;
      const short8 Ah0 = *reinterpret_cast<const short8*>(&ebuf[0][0 + g][ct * 16 + i16][0]);
      const short8 Ah1 = *reinterpret_cast<const short8*>(&ebuf[0][4 + g][ct * 16 + i16][0]);
      const short8 Al0 = *reinterpret_cast<const short8*>(&ebuf[1][0 + g][ct * 16 + i16][0]);
      const short8 Al1 = *reinterpret_cast<const short8*>(&ebuf[1][4 + g][ct * 16 + i16][0]);
      const f32x4 enf = reinterpret_cast<const f32x4*>(en_s)[tile * 4 + g];
      f32x4 acc[4];
      #pragma unroll
      for (int p = 0; p < 4; ++p) { acc[p][0] = 0.f; acc[p][1] = 0.f; acc[p][2] = 0.f; acc[p][3] = 0.f; }
      // per-acc order identical to round 5: hh0, hh1, hl0, hl1, lh0, lh1
      #pragma unroll
      for (int p = 0; p < 4; ++p) acc[p] = __builtin_amdgcn_mfma_f32_16x16x32_bf16(Ah0, Bh[p][0], acc[p], 0, 0, 0);
      #pragma unroll
      for (int p = 0; p < 4; ++p) acc[p] = __builtin_amdgcn_mfma_f32_16x16x32_bf16(Ah1, Bh[p][1], acc[p], 0, 0, 0);
      #pragma unroll
      for (int p = 0; p < 4; ++p) acc[p] = __builtin_amdgcn_mfma_f32_16x16x32_bf16(Ah0, Bl[p][0], acc[p], 0, 0, 0);
      #pragma unroll
      for (int p = 0; p < 4; ++p) acc[p] = __builtin_amdgcn_mfma_f32_16x16x32_bf16(Ah1, Bl[p][1], acc[p], 0, 0, 0);
      #pragma unroll
      for (int p = 0; p < 4; ++p) acc[p] = __builtin_amdgcn_mfma_f32_16x16x32_bf16(Al0, Bh[p][0], acc[p], 0, 0, 0);
      #pragma unroll
      for (int p = 0; p < 4; ++p) acc[p] = __builtin_amdgcn_mfma_f32_16x16x32_bf16(Al1, Bh[p][1], acc[p], 0, 0, 0);
      #pragma unroll
      for (int p = 0; p < 4; ++p) {
        #pragma unroll
        for (int r = 0; r < 4; ++r) {
          const float d = fmaf(-2.0f, acc[p][r], enf[r]);
          const bool lt = d < bd[p][r];
          bd2[p][r] = fminf(bd2[p][r], fmaxf(d, bd[p][r]));
          bd[p][r]  = fminf(bd[p][r], d);
          bt[p][r]  = lt ? tile : bt[p][r];
        }
      }
    }
  }

  // ---- finalize per ptile: merge 4 reg-streams, then 4 lane-groups ----
  const unsigned long long lanebit = 1ull << lane;
  #pragma unroll
  for (int p = 0; p < 4; ++p) {
    float fb = bd[p][0];
    float f2 = bd2[p][0];
    int   fk = bt[p][0] * 16 + g * 4 + 0;
    #pragma unroll
    for (int r = 1; r < 4; ++r) {
      const float dr = bd[p][r];
      const int   kr = bt[p][r] * 16 + g * 4 + r;
      f2 = fminf(fminf(f2, bd2[p][r]), fmaxf(fb, dr));
      const bool take = dr < fb;   // cross-stream ties land inside MARGIN -> rescued
      fb = take ? dr : fb;
      fk = take ? kr : fk;
    }
    #pragma unroll
    for (int m = 16; m <= 32; m <<= 1) {
      const float od = __shfl_xor(fb, m, 64);
      const int   ok = __shfl_xor(fk, m, 64);
      const float o2 = __shfl_xor(f2, m, 64);
      f2 = fminf(fminf(f2, o2), fmaxf(fb, od));
      const bool take = (od < fb) || (od == fb && ok < fk);
      fb = take ? od : fb;
      fk = take ? ok : fk;
    }
    if (g == 0) klds[wave * 64 + p * 16 + i16] = fk;
    // risky append (g==0 lanes represent the 16 points)
    const bool risky = (g == 0) && (f2 - fb <= MARGIN);
    const unsigned long long msk = __ballot(risky);
    if (msk) {
      unsigned basev = 0;
      if (lane == 0) basev = atomicAdd(cnt, (unsigned)__popcll(msk));
      basev = (unsigned)__shfl((int)basev, 0, 64);
      if (risky) {
        const unsigned pos = basev + (unsigned)__popcll(msk & (lanebit - 1));
        if (pos < listcap) list[pos] = (unsigned)(pbase + p * 16 + i16);
      }
    }
  }
  __syncthreads();

  // ---- epilogue: thread t owns point pbase0+t; full-wave 256B-contiguous
  // channel stores (round-4-verified clean write pattern) ----
  const int np = blockIdx.x * PTS + t;
  const int kwin = klds[t];
  const float4* er = reinterpret_cast<const float4*>(emb + (kwin << 6));
  #pragma unroll
  for (int jj = 0; jj < 16; ++jj) {
    float4 v = er[jj];
    out[(size_t)(4 * jj + 0) * Npts + np] = v.x;
    out[(size_t)(4 * jj + 1) * Npts + np] = v.y;
    out[(size_t)(4 * jj + 2) * Npts + np] = v.z;
    out[(size_t)(4 * jj + 3) * Npts + np] = v.w;
  }
}

// ---------- fallback: exact round-1 arithmetic for risky points (1 wave/point) ----------
__global__ __launch_bounds__(256) void vq_fix(
    const float* __restrict__ ze, const float* __restrict__ emb,
    const float* __restrict__ en, float* __restrict__ out,
    const unsigned int* __restrict__ cnt, const unsigned int* __restrict__ list,
    unsigned int listcap) {
  __shared__ float en_s[Kcb];
  const int t = threadIdx.x;
  const int wave = t >> 6, lane = t & 63;
  #pragma unroll
  for (int r = 0; r < 4; ++r) en_s[t + 256 * r] = en[t + 256 * r];
  __syncthreads();
  unsigned count = *cnt;
  if (count > listcap) count = listcap;
  const int wid = __builtin_amdgcn_readfirstlane(blockIdx.x * 4 + wave);
  for (unsigned i = wid; i < count; i += 256) {
    const int n = (int)list[i];
    const int b = n >> 12, hw = n & (HWs - 1);
    const float* xp = ze + (size_t)b * (Cdim * HWs) + hw;
    float x[Cdim];
    #pragma unroll
    for (int c = 0; c < Cdim; ++c) x[c] = xp[c * HWs];
    float xn0 = 0.f, xn1 = 0.f, xn2 = 0.f, xn3 = 0.f;
    #pragma unroll
    for (int c = 0; c < Cdim; c += 4) {
      xn0 = fmaf(x[c], x[c], xn0);         xn1 = fmaf(x[c + 1], x[c + 1], xn1);
      xn2 = fmaf(x[c + 2], x[c + 2], xn2); xn3 = fmaf(x[c + 3], x[c + 3], xn3);
    }
    const float xnorm = (xn0 + xn1) + (xn2 + xn3);
    float best = 3.4e38f; int bestk = 0;
    for (int kk = 0; kk < 16; ++kk) {
      const int k = lane * 16 + kk;
      const float4* er2 = reinterpret_cast<const float4*>(emb + (k << 6));
      float d0 = 0.f, d1 = 0.f, d2 = 0.f, d3 = 0.f;
      #pragma unroll
      for (int j = 0; j < 16; ++j) {
        float4 v = er2[j];
        d0 = fmaf(x[4 * j + 0], v.x, d0); d1 = fmaf(x[4 * j + 1], v.y, d1);
        d2 = fmaf(x[4 * j + 2], v.z, d2); d3 = fmaf(x[4 * j + 3], v.w, d3);
      }
      const float dot = (d0 + d1) + (d2 + d3);
      const float tt = xnorm + en_s[k];
      const float d = __fsub_rn(tt, __fmul_rn(2.0f, dot));
      if (d < best) { best = d; bestk = k; }
    }
    #pragma unroll
    for (int m = 1; m < 64; m <<= 1) {
      const float od = __shfl_xor(best, m, 64);
      const int   ok = __shfl_xor(bestk, m, 64);
      const bool take = (od < best) || (od == best && ok < bestk);
      best = take ? od : best;
      bestk = take ? ok : bestk;
    }
    out[(size_t)lane * Npts + n] = emb[(bestk << 6) + lane];
  }
}

// ---------- safety net (ws too small): round-4 proven kernel ----------
__global__ __launch_bounds__(256) void vq_direct(
    const float* __restrict__ ze, const float* __restrict__ emb, float* __restrict__ out) {
  __shared__ float en_s[Kcb];
  __shared__ float bestd_s[4][64];
  __shared__ int   bestk_s[4][64];
  const int t = threadIdx.x, wave = t >> 6, lane = t & 63;
  #pragma unroll
  for (int r = 0; r < 4; ++r) {
    const int k = t + r * 256;
    const float4* row = reinterpret_cast<const float4*>(emb + (k << 6));
    float a0 = 0.f, a1 = 0.f, a2 = 0.f, a3 = 0.f;
    #pragma unroll
    for (int j = 0; j < 16; ++j) {
      float4 v = row[j];
      a0 = fmaf(v.x, v.x, a0); a1 = fmaf(v.y, v.y, a1);
      a2 = fmaf(v.z, v.z, a2); a3 = fmaf(v.w, v.w, a3);
    }
    en_s[k] = (a0 + a1) + (a2 + a3);
  }
  __syncthreads();
  const int n = blockIdx.x * 64 + lane;
  const int b = n >> 12, hw = n & (HWs - 1);
  const float* xp = ze + (b * Cdim) * HWs + hw;
  float x[Cdim];
  #pragma unroll
  for (int c = 0; c < Cdim; ++c) x[c] = xp[c * HWs];
  float xn0 = 0.f, xn1 = 0.f, xn2 = 0.f, xn3 = 0.f;
  #pragma unroll
  for (int c = 0; c < Cdim; c += 4) {
    xn0 = fmaf(x[c], x[c], xn0); xn1 = fmaf(x[c + 1], x[c + 1], xn1);
    xn2 = fmaf(x[c + 2], x[c + 2], xn2); xn3 = fmaf(x[c + 3], x[c + 3], xn3);
  }
  const float xnorm = (xn0 + xn1) + (xn2 + xn3);
  const int wu = __builtin_amdgcn_readfirstlane(wave);
  const int kbase = wu * 256;
  float best = 3.4e38f; int bestk = 0;
  #pragma unroll 2
  for (int kk = 0; kk < 256; ++kk) {
    const int k = kbase + kk;
    const float4* er = reinterpret_cast<const float4*>(emb + (k << 6));
    float d0 = 0.f, d1 = 0.f, d2 = 0.f, d3 = 0.f;
    #pragma unroll
    for (int j = 0; j < 16; ++j) {
      float4 v = er[j];
      d0 = fmaf(x[4 * j + 0], v.x, d0); d1 = fmaf(x[4 * j + 1], v.y, d1);
      d2 = fmaf(x[4 * j + 2], v.z, d2); d3 = fmaf(x[4 * j + 3], v.w, d3);
    }
    const float dot = (d0 + d1) + (d2 + d3);
    const float tt = xnorm + en_s[k];
    const float d = __fsub_rn(tt, __fmul_rn(2.0f, dot));
    if (d < best) { best = d; bestk = k; }
  }
  bestd_s[wave][lane] = best; bestk_s[wave][lane] = bestk;
  __syncthreads();
  float bdv = bestd_s[0][lane]; int bkv = bestk_s[0][lane];
  #pragma unroll
  for (int w = 1; w < 4; ++w) {
    const float dw = bestd_s[w][lane]; const int kw = bestk_s[w][lane];
    if (dw < bdv) { bdv = dw; bkv = kw; }
  }
  const int np = blockIdx.x * 64 + lane;
  const int c0 = wave * 16;
  const float4* brow = reinterpret_cast<const float4*>(emb + (bkv << 6) + c0);
  #pragma unroll
  for (int j = 0; j < 4; ++j) {
    float4 v = brow[j];
    out[(c0 + 4 * j + 0) * Npts + np] = v.x;
    out[(c0 + 4 * j + 1) * Npts + np] = v.y;
    out[(c0 + 4 * j + 2) * Npts + np] = v.z;
    out[(c0 + 4 * j + 3) * Npts + np] = v.w;
  }
}

extern "C" void kernel_launch(void* const* d_in, const int* in_sizes, int n_in,
                              void* d_out, int out_size, void* d_ws, size_t ws_size,
                              hipStream_t stream) {
  (void)in_sizes; (void)n_in; (void)out_size;
  const float* ze  = (const float*)d_in[0];
  const float* emb = (const float*)d_in[1];
  float* out = (float*)d_out;

  if (ws_size < WS_NEED) {   // safety net: proven round-4 path
    vq_direct<<<Npts / 64, 256, 0, stream>>>(ze, emb, out);
    return;
  }
  unsigned char* ws = (unsigned char*)d_ws;
  unsigned short* eh = (unsigned short*)(ws + WS_EH);
  unsigned short* el = (unsigned short*)(ws + WS_EL);
  float* en          = (float*)(ws + WS_EN);
  unsigned* cnt      = (unsigned*)(ws + WS_CNT);
  unsigned* list     = (unsigned*)(ws + WS_LIST);

  hipMemsetAsync(cnt, 0, 4, stream);
  vq_prep<<<Kcb / 64, 64, 0, stream>>>(emb, eh, el, en);
  vq_main<<<Npts / PTS, 256, 0, stream>>>(ze, emb, eh, el, en, out, cnt, list, (unsigned)Npts);
  vq_fix<<<64, 256, 0, stream>>>(ze, emb, en, out, cnt, list, (unsigned)Npts);
}